// Round 1
// 246.301 us; speedup vs baseline: 1.0644x; 1.0644x over previous
//
#include <hip/hip_runtime.h>

// LinearAttention MI355X: B=2, C=96, N=131072 (x stored [B,C,N], N contiguous),
// 8 heads x hd=12. MFMA fp16, latency-optimized restructure:
//  - B-fragments (x) loaded global->register directly (no xs staging, no barriers)
//  - A-fragments (W, M) read per-k-step from fp16 copies (wcvt pre-kernel), L1-resident
//  - LDS only holds what MUST be transposed across waves: ke/vl (p1), q logits (p3)
//  - 128-half row stride + XOR swizzle ((row&7)<<4): row-varying lane reads <=2-way
//  - p1: 49152 B LDS -> 3 blocks/CU; p3: 32768 B -> 4 blocks/CU
//
// Fragment layouts (gfx950, verified learn_hip m89/m118/m120):
//   A[m=lane&15][k=quad*8+j], B[k=quad*8+j][n=lane&15], C/D row=quad*4+reg col=lane&15

typedef _Float16 half_t;
typedef _Float16 half8 __attribute__((ext_vector_type(8)));
typedef float f32x4 __attribute__((ext_vector_type(4)));

#define MFMA16 __builtin_amdgcn_mfma_f32_16x16x32_f16
#define NSH 17
#define NP 16   // partial reduction buffers

// swizzled byte offset in a [row][128 halves] LDS tile (16B-block XOR keeps b128 alignment)
__device__ __forceinline__ int swz(int row, int colh) {
  return (row * 256 + colh * 2) ^ ((row & 7) << 4);
}

// ---------------- pass 0: weights fp32 -> fp16 ----------------
__global__ void wcvt(const float* __restrict__ Wq, const float* __restrict__ Wk,
                     const float* __restrict__ Wv, half_t* __restrict__ WqH,
                     half_t* __restrict__ WkH, half_t* __restrict__ WvH) {
  const int g = blockIdx.x * 256 + threadIdx.x;   // 36*256 = 9216 exactly
  WqH[g] = (half_t)Wq[g];
  WkH[g] = (half_t)Wk[g];
  WvH[g] = (half_t)Wv[g];
}

// ---------------- pass 1: k,v GEMMs + context ----------------
__global__ __launch_bounds__(256, 3)
void p1(const float* __restrict__ x, const half_t* __restrict__ Wk,
        const half_t* __restrict__ Wv, float* __restrict__ part) {
  // LDS: ke [96][128]h swizzled @0 (24576 B), vl @24576. total 49152 -> 3 blocks/CU
  __shared__ __align__(16) char smem[49152];

  const int tid  = threadIdx.x;
  const int lane = tid & 63, l15 = lane & 15, quad = lane >> 4, wid = tid >> 6;
  const int b  = blockIdx.x >> 10;
  const int n0 = (blockIdx.x & 1023) << 7;

  // ---- x B-fragments straight to registers (48 scalar f32 loads, all independent)
  float xv[48];
  {
    const float* xb = x + (((size_t)(b * 96 + quad * 8)) << NSH) + n0 + wid * 32 + l15;
#pragma unroll
    for (int ks = 0; ks < 3; ++ks)
#pragma unroll
      for (int j = 0; j < 8; ++j)
#pragma unroll
        for (int ct = 0; ct < 2; ++ct)
          xv[(ks * 8 + j) * 2 + ct] = xb[(((size_t)(ks * 32 + j)) << NSH) + ct * 16];
  }
  half8 bf[3][2];
#pragma unroll
  for (int ks = 0; ks < 3; ++ks)
#pragma unroll
    for (int ct = 0; ct < 2; ++ct)
#pragma unroll
      for (int j = 0; j < 8; ++j)
        bf[ks][ct][j] = (half_t)xv[(ks * 8 + j) * 2 + ct];

  f32x4 acc[6][2];
  // ---- k GEMM: D[c_out][n], A from fp16 Wk in global (L1-resident 18KB) ----
#pragma unroll
  for (int rt = 0; rt < 6; ++rt)
#pragma unroll
    for (int ct = 0; ct < 2; ++ct) acc[rt][ct] = (f32x4){0.f, 0.f, 0.f, 0.f};
#pragma unroll
  for (int ks = 0; ks < 3; ++ks) {
    half8 af[6];
#pragma unroll
    for (int rt = 0; rt < 6; ++rt)
      af[rt] = *(const half8*)&Wk[(rt * 16 + l15) * 96 + ks * 32 + quad * 8];
#pragma unroll
    for (int rt = 0; rt < 6; ++rt)
#pragma unroll
      for (int ct = 0; ct < 2; ++ct)
        acc[rt][ct] = MFMA16(af[rt], bf[ks][ct], acc[rt][ct], 0, 0, 0);
  }
  // k epilogue: exp -> ke[c][n] (swizzled)
#pragma unroll
  for (int rt = 0; rt < 6; ++rt)
#pragma unroll
    for (int ct = 0; ct < 2; ++ct)
#pragma unroll
      for (int i = 0; i < 4; ++i) {
        int row = rt * 16 + quad * 4 + i;
        int col = (wid * 2 + ct) * 16 + l15;
        *(half_t*)(smem + swz(row, col)) = (half_t)__expf(acc[rt][ct][i]);
      }

  // ---- v GEMM (reuse bf, acc) ----
#pragma unroll
  for (int rt = 0; rt < 6; ++rt)
#pragma unroll
    for (int ct = 0; ct < 2; ++ct) acc[rt][ct] = (f32x4){0.f, 0.f, 0.f, 0.f};
#pragma unroll
  for (int ks = 0; ks < 3; ++ks) {
    half8 af[6];
#pragma unroll
    for (int rt = 0; rt < 6; ++rt)
      af[rt] = *(const half8*)&Wv[(rt * 16 + l15) * 96 + ks * 32 + quad * 8];
#pragma unroll
    for (int rt = 0; rt < 6; ++rt)
#pragma unroll
      for (int ct = 0; ct < 2; ++ct)
        acc[rt][ct] = MFMA16(af[rt], bf[ks][ct], acc[rt][ct], 0, 0, 0);
  }
#pragma unroll
  for (int rt = 0; rt < 6; ++rt)
#pragma unroll
    for (int ct = 0; ct < 2; ++ct)
#pragma unroll
      for (int i = 0; i < 4; ++i) {
        int row = rt * 16 + quad * 4 + i;
        int col = (wid * 2 + ct) * 16 + l15;
        *(half_t*)(smem + 24576 + swz(row, col)) = (half_t)acc[rt][ct][i];
      }
  __syncthreads();   // the ONLY barrier in p1

  // ---- context via MFMA over tokens: wave wid handles heads 2w, 2w+1 ----
  // ctx[d][e] = sum_n ke[h12+d][n] * vl[h12+e][n]; rows clamped (m>=12 lanes discarded)
  float* dst = part + (size_t)((blockIdx.x & (NP - 1)) * 2 + b) * 1248;
#pragma unroll
  for (int hh = 0; hh < 2; ++hh) {
    const int h = wid * 2 + hh;
    int row = h * 12 + l15; row = row > 95 ? 95 : row;
    f32x4 c = (f32x4){0.f, 0.f, 0.f, 0.f};
#pragma unroll
    for (int ks = 0; ks < 4; ++ks) {
      const int off = swz(row, ks * 32 + quad * 8);
      half8 a  = *(const half8*)(smem + off);
      half8 bv = *(const half8*)(smem + 24576 + off);
      c = MFMA16(a, bv, c, 0, 0, 0);
    }
#pragma unroll
    for (int i = 0; i < 4; ++i) {
      int d = quad * 4 + i, e = l15;
      if (d < 12 && e < 12) atomicAdd(&dst[h * 144 + d * 12 + e], c[i]);
    }
  }
  // ---- S row sums (threads 0..95): S[c] = sum_n ke[c][n] (block order irrelevant) ----
  if (tid < 96) {
    float s = 0.f;
#pragma unroll
    for (int j = 0; j < 16; ++j) {
      half8 v = *(const half8*)(smem + swz(tid, j * 8));
#pragma unroll
      for (int e = 0; e < 8; ++e) s += (float)v[e];
    }
    atomicAdd(&dst[1152 + tid], s);
  }
}

// ---------------- pass 2: fold Wproj into tiny context (fp16 output) ----------------
__global__ void kB(const float* __restrict__ part, const float* __restrict__ Wproj,
                   half_t* __restrict__ Mt) {
  const int g = blockIdx.x * 256 + threadIdx.x;   // 2*96*96 = 18432 exactly
  const int b = g / (96 * 96);
  const int rem = g % (96 * 96);
  const int o = rem / 96;
  const int r = rem % 96;        // r = h*12+d
  const int h = r / 12, d = r % 12;
  float s = 0.f;
#pragma unroll
  for (int p = 0; p < NP; ++p) s += part[(size_t)(p * 2 + b) * 1248 + 1152 + r];
  float acc = 0.f;
#pragma unroll
  for (int e = 0; e < 12; ++e) {
    float ce = 0.f;
#pragma unroll
    for (int p = 0; p < NP; ++p)
      ce += part[(size_t)(p * 2 + b) * 1248 + h * 144 + d * 12 + e];
    acc = fmaf(ce, Wproj[o * 96 + h * 12 + e], acc);
  }
  Mt[(size_t)(b * 96 + o) * 96 + r] = (half_t)(acc / s);
}

// ---------------- pass 3: q GEMM + softmax + out GEMM ----------------
__global__ __launch_bounds__(256, 4)
void p3(const float* __restrict__ x, const half_t* __restrict__ Wq,
        const half_t* __restrict__ Mt, float* __restrict__ out) {
  // LDS: qs [128 tokens][128 ch]h swizzled = 32768 B -> 4 blocks/CU
  __shared__ __align__(16) char smem[32768];

  const int tid  = threadIdx.x;
  const int lane = tid & 63, l15 = lane & 15, quad = lane >> 4, wid = tid >> 6;
  const int b  = blockIdx.x >> 10;
  const int n0 = (blockIdx.x & 1023) << 7;

  float xv[48];
  {
    const float* xb = x + (((size_t)(b * 96 + quad * 8)) << NSH) + n0 + wid * 32 + l15;
#pragma unroll
    for (int ks = 0; ks < 3; ++ks)
#pragma unroll
      for (int j = 0; j < 8; ++j)
#pragma unroll
        for (int ct = 0; ct < 2; ++ct)
          xv[(ks * 8 + j) * 2 + ct] = xb[(((size_t)(ks * 32 + j)) << NSH) + ct * 16];
  }
  half8 bf[3][2];
#pragma unroll
  for (int ks = 0; ks < 3; ++ks)
#pragma unroll
    for (int ct = 0; ct < 2; ++ct)
#pragma unroll
      for (int j = 0; j < 8; ++j)
        bf[ks][ct][j] = (half_t)xv[(ks * 8 + j) * 2 + ct];

  f32x4 acc[6][2];
#pragma unroll
  for (int rt = 0; rt < 6; ++rt)
#pragma unroll
    for (int ct = 0; ct < 2; ++ct) acc[rt][ct] = (f32x4){0.f, 0.f, 0.f, 0.f};
#pragma unroll
  for (int ks = 0; ks < 3; ++ks) {
    half8 af[6];
#pragma unroll
    for (int rt = 0; rt < 6; ++rt)
      af[rt] = *(const half8*)&Wq[(rt * 16 + l15) * 96 + ks * 32 + quad * 8];
#pragma unroll
    for (int rt = 0; rt < 6; ++rt)
#pragma unroll
      for (int ct = 0; ct < 2; ++ct)
        acc[rt][ct] = MFMA16(af[rt], bf[ks][ct], acc[rt][ct], 0, 0, 0);
  }
  // q epilogue: logits transposed into qs[token][ch] (swizzled)
#pragma unroll
  for (int rt = 0; rt < 6; ++rt)
#pragma unroll
    for (int ct = 0; ct < 2; ++ct)
#pragma unroll
      for (int i = 0; i < 4; ++i) {
        int row = rt * 16 + quad * 4 + i;           // channel
        int col = (wid * 2 + ct) * 16 + l15;        // token
        *(half_t*)(smem + swz(col, row)) = (half_t)acc[rt][ct][i];
      }
  __syncthreads();

  // softmax over head dim: thread owns (token n, head-group hg of 4 heads)
  {
    const int n = tid & 127, hg = tid >> 7;
    float q[48];
#pragma unroll
    for (int j = 0; j < 6; ++j) {
      half8 v = *(const half8*)(smem + swz(n, hg * 48 + j * 8));
#pragma unroll
      for (int e = 0; e < 8; ++e) q[j * 8 + e] = (float)v[e];
    }
#pragma unroll
    for (int hh = 0; hh < 4; ++hh) {
      float* ql = q + hh * 12;
      float m = ql[0];
#pragma unroll
      for (int j = 1; j < 12; ++j) m = fmaxf(m, ql[j]);
      float s = 0.f;
#pragma unroll
      for (int j = 0; j < 12; ++j) { ql[j] = __expf(ql[j] - m); s += ql[j]; }
      const float inv = 1.0f / s;
#pragma unroll
      for (int j = 0; j < 12; ++j) ql[j] *= inv;
    }
#pragma unroll
    for (int j = 0; j < 6; ++j) {
      half8 w;
#pragma unroll
      for (int e = 0; e < 8; ++e) w[e] = (half_t)q[j * 8 + e];
      *(half8*)(smem + swz(n, hg * 48 + j * 8)) = w;
    }
  }
  __syncthreads();

  // out GEMM: D[o][n] = sum_r M[o][r] * q[r][n]; A = fp16 Mt (global), B from qs[n][r]
#pragma unroll
  for (int rt = 0; rt < 6; ++rt)
#pragma unroll
    for (int ct = 0; ct < 2; ++ct) acc[rt][ct] = (f32x4){0.f, 0.f, 0.f, 0.f};
#pragma unroll
  for (int ks = 0; ks < 3; ++ks) {
    half8 af[6], bq[2];
#pragma unroll
    for (int rt = 0; rt < 6; ++rt)
      af[rt] = *(const half8*)&Mt[(size_t)b * 9216 + (rt * 16 + l15) * 96 + ks * 32 + quad * 8];
#pragma unroll
    for (int ct = 0; ct < 2; ++ct)
      bq[ct] = *(const half8*)(smem + swz((wid * 2 + ct) * 16 + l15, ks * 32 + quad * 8));
#pragma unroll
    for (int rt = 0; rt < 6; ++rt)
#pragma unroll
      for (int ct = 0; ct < 2; ++ct)
        acc[rt][ct] = MFMA16(af[rt], bq[ct], acc[rt][ct], 0, 0, 0);
  }
#pragma unroll
  for (int rt = 0; rt < 6; ++rt)
#pragma unroll
    for (int ct = 0; ct < 2; ++ct)
#pragma unroll
      for (int i = 0; i < 4; ++i) {
        int row = rt * 16 + quad * 4 + i;
        int col = (wid * 2 + ct) * 16 + l15;
        out[(((size_t)(b * 96 + row)) << NSH) + n0 + col] = acc[rt][ct][i];
      }
}

extern "C" void kernel_launch(void* const* d_in, const int* in_sizes, int n_in,
                              void* d_out, int out_size, void* d_ws, size_t ws_size,
                              hipStream_t stream) {
  const float* x     = (const float*)d_in[0];
  const float* Wq    = (const float*)d_in[1];
  const float* Wk    = (const float*)d_in[2];
  const float* Wv    = (const float*)d_in[3];
  const float* Wproj = (const float*)d_in[4];
  float* out = (float*)d_out;
  float* ws  = (float*)d_ws;

  float*  part = ws;                                   // NP*2*1248 f32  = 159744 B
  half_t* Mt   = (half_t*)(ws + NP * 2 * 1248);        // 2*96*96 h     = 36864 B
  half_t* WqH  = (half_t*)(ws + NP * 2 * 1248 + 9216); // 9216 h each
  half_t* WkH  = WqH + 9216;
  half_t* WvH  = WkH + 9216;

  hipMemsetAsync(part, 0, NP * 2 * 1248 * sizeof(float), stream);
  wcvt<<<36, 256, 0, stream>>>(Wq, Wk, Wv, WqH, WkH, WvH);
  p1<<<2048, 256, 0, stream>>>(x, WkH, WvH, part);
  kB<<<72, 256, 0, stream>>>(part, Wproj, Mt);
  p3<<<2048, 256, 0, stream>>>(x, WqH, Mt, out);
}